// Round 1
// baseline (2415.025 us; speedup 1.0000x reference)
//
#include <hip/hip_runtime.h>

// SJModel: 3x3 SAME conv (fp32, no bias) + 8-step LIF (tau=2, hard reset, v_th=1)
// Shapes: x[T=8][B=16][Cin=64][H=64][W=64], W[Cout=64][Cin=64][3][3]
// out = spikes [T][B][Cout=64][H][W] fp32 (0.0/1.0)

#define T_STEPS 8
#define B_SZ    16
#define CIN     64
#define COUT    64
#define H_SZ    64
#define W_SZ    64
#define CO_BLK  32   // output channels per block (2 co-chunks)

// Transpose W[co][ci][kh][kw] -> wt[ci][kh][kw][co] so the main kernel can
// read 32 contiguous lane-uniform weights per tap (scalar loads -> SGPRs).
__global__ void wt_transpose(const float* __restrict__ W, float* __restrict__ wt) {
    int idx = blockIdx.x * blockDim.x + threadIdx.x;
    if (idx >= COUT * CIN * 9) return;
    int kw = idx % 3;
    int kh = (idx / 3) % 3;
    int ci = (idx / 9) % CIN;
    int co = idx / (9 * CIN);
    wt[((ci * 3 + kh) * 3 + kw) * COUT + co] = W[idx];
}

__global__ void __launch_bounds__(256)
lif_conv(const float* __restrict__ x, const float* __restrict__ wt,
         float* __restrict__ out) {
    const int w  = threadIdx.x;        // 0..63 (lane = W dim -> coalesced)
    const int ty = threadIdx.y;        // 0..3
    const int hb = blockIdx.x;         // 0..15 : h stripe of 4 rows
    const int b  = blockIdx.y;         // 0..15
    const int cb = blockIdx.z;         // 0..1  : co chunk
    const int h  = hb * 4 + ty;
    const int coBase = cb * CO_BLK;

    // persistent membrane potential per (pixel, co)
    float v[CO_BLK];
#pragma unroll
    for (int j = 0; j < CO_BLK; ++j) v[j] = 0.f;

    for (int t = 0; t < T_STEPS; ++t) {
        const float* xt = x + (size_t)(t * B_SZ + b) * CIN * (H_SZ * W_SZ);

        float acc[CO_BLK];
#pragma unroll
        for (int j = 0; j < CO_BLK; ++j) acc[j] = 0.f;

        for (int ci = 0; ci < CIN; ++ci) {
            const float* xc = xt + (size_t)ci * (H_SZ * W_SZ);
#pragma unroll
            for (int kh = 0; kh < 3; ++kh) {
                const int ih = h + kh - 1;
                const bool hv = (unsigned)ih < (unsigned)H_SZ;
#pragma unroll
                for (int kw = 0; kw < 3; ++kw) {
                    const int iw = w + kw - 1;
                    float xv = 0.f;
                    if (hv && (unsigned)iw < (unsigned)W_SZ)
                        xv = xc[ih * W_SZ + iw];
                    // lane-uniform weight pointer -> scalar loads
                    const float* wp = wt + ((ci * 3 + kh) * 3 + kw) * COUT + coBase;
#pragma unroll
                    for (int j = 0; j < CO_BLK; ++j)
                        acc[j] = fmaf(xv, wp[j], acc[j]);
                }
            }
        }

        // LIF: charge (np op order), fire, hard reset; write spikes
        size_t obase = ((size_t)(t * B_SZ + b) * COUT + coBase) * (H_SZ * W_SZ)
                     + (size_t)h * W_SZ + w;
#pragma unroll
        for (int j = 0; j < CO_BLK; ++j) {
            float vv = v[j];
            float d  = (acc[j] - vv) * 0.5f;   // (z - v)/tau, /2 == *0.5 exact
            vv = vv + d;                        // charge
            float s  = (vv - 1.0f >= 0.f) ? 1.f : 0.f;  // fire
            vv = (s != 0.f) ? 0.f : vv;         // hard reset
            v[j] = vv;
            out[obase + (size_t)j * (H_SZ * W_SZ)] = s;
        }
    }
}

extern "C" void kernel_launch(void* const* d_in, const int* in_sizes, int n_in,
                              void* d_out, int out_size, void* d_ws, size_t ws_size,
                              hipStream_t stream) {
    const float* x  = (const float*)d_in[0];
    const float* W  = (const float*)d_in[1];
    float* out = (float*)d_out;
    float* wt  = (float*)d_ws;   // 64*64*9*4 = 147456 B of scratch

    wt_transpose<<<dim3((COUT * CIN * 9 + 255) / 256), dim3(256), 0, stream>>>(W, wt);
    lif_conv<<<dim3(16, 16, 2), dim3(64, 4, 1), 0, stream>>>(x, wt, out);
}

// Round 4
// 1109.110 us; speedup vs baseline: 2.1774x; 2.1774x over previous
//
#include <hip/hip_runtime.h>

// SJModel: 3x3 SAME conv (fp32, no bias) + 8-step LIF (tau=2, hard reset, v_th=1)
// x[T=8][B=16][Cin=64][H=64][W=64], W[Cout=64][Cin=64][3][3]
// out = spikes [T][B][Cout=64][H][W] fp32 (0/1)
//
// R2 (second resubmit after two infra failures): CO_BLK 32->16 (4 co-chunks
// in blockIdx.z) => 4096 waves = 4 waves/SIMD (was 2), hoisted x loads,
// weight layout [ci][kh][cb][kw][co16] for contiguous s_load of all 48
// weights per (ci,kh,cb).

#define T_STEPS 8
#define B_SZ    16
#define CIN     64
#define COUT    64
#define H_SZ    64
#define W_SZ    64
#define CO_BLK  16
#define NCB     (COUT / CO_BLK)   // 4 co-chunks

// W[co][ci][kh][kw] -> wt[ci][kh][cb][kw][j]  (48 contiguous per (ci,kh,cb))
__global__ void wt_transpose(const float* __restrict__ W, float* __restrict__ wt) {
    int idx = blockIdx.x * blockDim.x + threadIdx.x;
    if (idx >= COUT * CIN * 9) return;
    int kw = idx % 3;
    int kh = (idx / 3) % 3;
    int ci = (idx / 9) % CIN;
    int co = idx / (9 * CIN);
    int cb = co / CO_BLK, j = co % CO_BLK;
    wt[((((ci * 3 + kh) * NCB + cb) * 3) + kw) * CO_BLK + j] = W[idx];
}

__global__ void __launch_bounds__(256, 4)
lif_conv(const float* __restrict__ x, const float* __restrict__ wt,
         float* __restrict__ out) {
    const int w  = threadIdx.x;          // 0..63, lane = W dim (coalesced)
    const int ty = threadIdx.y;          // 0..3  (one wave per h-row)
    const int h  = blockIdx.x * 4 + ty;  // 0..63
    const int b  = blockIdx.y;           // 0..15
    const int cb = blockIdx.z;           // 0..3 co-chunk

    float v[CO_BLK];
#pragma unroll
    for (int j = 0; j < CO_BLK; ++j) v[j] = 0.f;

    const bool wm0 = (w > 0), wm2 = (w < W_SZ - 1);

    for (int t = 0; t < T_STEPS; ++t) {
        const float* xt = x + (size_t)(t * B_SZ + b) * CIN * (H_SZ * W_SZ);

        float acc[CO_BLK];
#pragma unroll
        for (int j = 0; j < CO_BLK; ++j) acc[j] = 0.f;

#pragma unroll 2
        for (int ci = 0; ci < CIN; ++ci) {
            const float* xc = xt + ci * (H_SZ * W_SZ) + h * W_SZ + w;

            // hoist all 9 taps' x values before the FMA burst
            float xv[3][3];
#pragma unroll
            for (int kh = 0; kh < 3; ++kh) {
                const int ih = h + kh - 1;
                const bool hv = (unsigned)ih < (unsigned)H_SZ;
                const float* xr = xc + (kh - 1) * W_SZ;
                xv[kh][0] = (hv && wm0) ? xr[-1] : 0.f;
                xv[kh][1] = hv ? xr[0] : 0.f;
                xv[kh][2] = (hv && wm2) ? xr[1] : 0.f;
            }

#pragma unroll
            for (int kh = 0; kh < 3; ++kh) {
                // 48 contiguous lane-uniform weights for this (ci,kh,cb)
                const float* wr = wt + (size_t)(((ci * 3 + kh) * NCB + cb) * 3) * CO_BLK;
#pragma unroll
                for (int kw = 0; kw < 3; ++kw) {
                    const float xvv = xv[kh][kw];
#pragma unroll
                    for (int j = 0; j < CO_BLK; ++j)
                        acc[j] = fmaf(xvv, wr[kw * CO_BLK + j], acc[j]);
                }
            }
        }

        // LIF: charge (np op order), fire, hard reset; write spikes
        size_t obase = ((size_t)(t * B_SZ + b) * COUT + cb * CO_BLK) * (H_SZ * W_SZ)
                     + (size_t)h * W_SZ + w;
#pragma unroll
        for (int j = 0; j < CO_BLK; ++j) {
            float vv = v[j];
            vv = vv + (acc[j] - vv) * 0.5f;          // charge: v + (z-v)/2
            float s = (vv >= 1.0f) ? 1.f : 0.f;      // fire (v-1>=0 <=> v>=1)
            vv = (vv >= 1.0f) ? 0.f : vv;            // hard reset
            v[j] = vv;
            out[obase + (size_t)j * (H_SZ * W_SZ)] = s;
        }
    }
}

extern "C" void kernel_launch(void* const* d_in, const int* in_sizes, int n_in,
                              void* d_out, int out_size, void* d_ws, size_t ws_size,
                              hipStream_t stream) {
    const float* x  = (const float*)d_in[0];
    const float* W  = (const float*)d_in[1];
    float* out = (float*)d_out;
    float* wt  = (float*)d_ws;   // 64*64*9*4 = 147456 B scratch

    wt_transpose<<<dim3((COUT * CIN * 9 + 255) / 256), dim3(256), 0, stream>>>(W, wt);
    lif_conv<<<dim3(16, 16, 4), dim3(64, 4, 1), 0, stream>>>(x, wt, out);
}

// Round 5
// 958.398 us; speedup vs baseline: 2.5199x; 1.1573x over previous
//
#include <hip/hip_runtime.h>

// SJModel: 3x3 SAME conv (fp32, no bias) + 8-step LIF (tau=2, hard reset, v_th=1)
// x[T=8][B=16][Cin=64][H=64][W=64], W[Cout=64][Cin=64][3][3]
// out = spikes [T][B][Cout=64][H][W] fp32 (0/1)
//
// R5: CO_BLK 16->8 (8 co-chunks in blockIdx.z) => 2048 blocks = 8 blocks/CU
//     = 8 waves/SIMD target occupancy (was 4). Accumulation order per output
//     unchanged => bitwise-identical spikes vs R2/R4.

#define T_STEPS 8
#define B_SZ    16
#define CIN     64
#define COUT    64
#define H_SZ    64
#define W_SZ    64
#define CO_BLK  8
#define NCB     (COUT / CO_BLK)   // 8 co-chunks

// W[co][ci][kh][kw] -> wt[ci][kh][cb][kw][j]  (24 contiguous per (ci,kh,cb))
__global__ void wt_transpose(const float* __restrict__ W, float* __restrict__ wt) {
    int idx = blockIdx.x * blockDim.x + threadIdx.x;
    if (idx >= COUT * CIN * 9) return;
    int kw = idx % 3;
    int kh = (idx / 3) % 3;
    int ci = (idx / 9) % CIN;
    int co = idx / (9 * CIN);
    int cb = co / CO_BLK, j = co % CO_BLK;
    wt[((((ci * 3 + kh) * NCB + cb) * 3) + kw) * CO_BLK + j] = W[idx];
}

__global__ void __launch_bounds__(256, 8)
lif_conv(const float* __restrict__ x, const float* __restrict__ wt,
         float* __restrict__ out) {
    const int w  = threadIdx.x;          // 0..63, lane = W dim (coalesced)
    const int ty = threadIdx.y;          // 0..3  (one wave per h-row)
    const int h  = blockIdx.x * 4 + ty;  // 0..63
    const int b  = blockIdx.y;           // 0..15
    const int cb = blockIdx.z;           // 0..7 co-chunk

    float v[CO_BLK];
#pragma unroll
    for (int j = 0; j < CO_BLK; ++j) v[j] = 0.f;

    const bool wm0 = (w > 0), wm2 = (w < W_SZ - 1);

    for (int t = 0; t < T_STEPS; ++t) {
        const float* xt = x + (size_t)(t * B_SZ + b) * CIN * (H_SZ * W_SZ);

        float acc[CO_BLK];
#pragma unroll
        for (int j = 0; j < CO_BLK; ++j) acc[j] = 0.f;

#pragma unroll 2
        for (int ci = 0; ci < CIN; ++ci) {
            const float* xc = xt + ci * (H_SZ * W_SZ) + h * W_SZ + w;

            // hoist all 9 taps' x values before the FMA burst
            float xv[3][3];
#pragma unroll
            for (int kh = 0; kh < 3; ++kh) {
                const int ih = h + kh - 1;
                const bool hv = (unsigned)ih < (unsigned)H_SZ;
                const float* xr = xc + (kh - 1) * W_SZ;
                xv[kh][0] = (hv && wm0) ? xr[-1] : 0.f;
                xv[kh][1] = hv ? xr[0] : 0.f;
                xv[kh][2] = (hv && wm2) ? xr[1] : 0.f;
            }

#pragma unroll
            for (int kh = 0; kh < 3; ++kh) {
                // 24 contiguous lane-uniform weights for this (ci,kh,cb)
                const float* wr = wt + (size_t)(((ci * 3 + kh) * NCB + cb) * 3) * CO_BLK;
#pragma unroll
                for (int kw = 0; kw < 3; ++kw) {
                    const float xvv = xv[kh][kw];
#pragma unroll
                    for (int j = 0; j < CO_BLK; ++j)
                        acc[j] = fmaf(xvv, wr[kw * CO_BLK + j], acc[j]);
                }
            }
        }

        // LIF: charge (np op order), fire, hard reset; write spikes
        size_t obase = ((size_t)(t * B_SZ + b) * COUT + cb * CO_BLK) * (H_SZ * W_SZ)
                     + (size_t)h * W_SZ + w;
#pragma unroll
        for (int j = 0; j < CO_BLK; ++j) {
            float vv = v[j];
            vv = vv + (acc[j] - vv) * 0.5f;          // charge: v + (z-v)/2
            float s = (vv >= 1.0f) ? 1.f : 0.f;      // fire (v-1>=0 <=> v>=1)
            vv = (vv >= 1.0f) ? 0.f : vv;            // hard reset
            v[j] = vv;
            out[obase + (size_t)j * (H_SZ * W_SZ)] = s;
        }
    }
}

extern "C" void kernel_launch(void* const* d_in, const int* in_sizes, int n_in,
                              void* d_out, int out_size, void* d_ws, size_t ws_size,
                              hipStream_t stream) {
    const float* x  = (const float*)d_in[0];
    const float* W  = (const float*)d_in[1];
    float* out = (float*)d_out;
    float* wt  = (float*)d_ws;   // 64*64*9*4 = 147456 B scratch

    wt_transpose<<<dim3((COUT * CIN * 9 + 255) / 256), dim3(256), 0, stream>>>(W, wt);
    lif_conv<<<dim3(16, 16, 8), dim3(64, 4, 1), 0, stream>>>(x, wt, out);
}